// Round 6
// baseline (301.606 us; speedup 1.0000x reference)
//
#include <hip/hip_runtime.h>
#include <math.h>

#define BS 2
#define NQ 21760
#define V_LEN 21760
#define EMBED 256
#define NH 8
#define NL 4
#define NP 4
#define HD 32

typedef __bf16 bf16;
typedef __bf16 bf16x8 __attribute__((ext_vector_type(8)));
typedef __bf16 bf16x4 __attribute__((ext_vector_type(4)));
typedef float f32x4 __attribute__((ext_vector_type(4)));
typedef float f32x2 __attribute__((ext_vector_type(2)));
typedef unsigned int u32;

// async global->LDS, 16B per lane. LDS dest must be lane-linear (base + lane*16).
#define GLOAD_LDS16(gp, lp_) \
    __builtin_amdgcn_global_load_lds( \
        (const __attribute__((address_space(1))) unsigned int*)(gp), \
        (__attribute__((address_space(3))) unsigned int*)(lp_), 16, 0, 0)

// ---------------- fused prologue: LDS-tiled transpose+cast of all weights + bias concat
__global__ __launch_bounds__(256) void cast_all(
    const float* __restrict__ W_v, const float* __restrict__ W_off,
    const float* __restrict__ W_attn, const float* __restrict__ W_out,
    const float* __restrict__ b_off, const float* __restrict__ b_attn,
    bf16* __restrict__ WTv, bf16* __restrict__ WToa, bf16* __restrict__ WTu,
    float* __restrict__ bcat)
{
    const int bid = blockIdx.x;
    const int tid = threadIdx.x;
    if (bid == 56) {
        if (tid < 384) bcat[tid] = (tid < 256) ? b_off[tid] : b_attn[tid - 256];
        return;
    }
    const float* W; bf16* WT; int N, tile;
    if (bid < 16)      { W = W_v;    WT = WTv;           N = 256; tile = bid; }
    else if (bid < 32) { W = W_off;  WT = WToa;          N = 256; tile = bid - 16; }
    else if (bid < 40) { W = W_attn; WT = WToa + 65536;  N = 128; tile = bid - 32; }
    else               { W = W_out;  WT = WTu;           N = 256; tile = bid - 40; }
    const int ntn = N >> 6;
    const int k0 = (tile / ntn) * 64, n0 = (tile % ntn) * 64;

    __shared__ float lds[64][65];
    const int c = tid & 63, r4 = tid >> 6;
    #pragma unroll
    for (int p = 0; p < 16; p++) {
        int rr = r4 + p * 4;
        lds[rr][c] = W[(size_t)(k0 + rr) * N + n0 + c];   // coalesced 256B rows
    }
    __syncthreads();
    #pragma unroll
    for (int p = 0; p < 16; p++) {
        int i = r4 + p * 4;                                // n index
        WT[(size_t)(n0 + i) * 256 + k0 + c] = (bf16)lds[c][i];  // coalesced 128B rows
    }
}

// ---------------- merged vproj+offaw GEMM (fp32 A, K=256, tile 128x128, 2-phase dbuf)
// blocks [0, nblk1): vproj = value@WTv^T + b_v  -> per-head bf16 layout [b][h][v][32]
// blocks [nblk1, ..): offaw = query@WToa^T + bcat -> fp32 linear [M,384]
__global__ __launch_bounds__(256) void gemm_dual(
    const float* __restrict__ A1, const bf16* __restrict__ WT1,
    const float* __restrict__ bias1, void* __restrict__ C1,
    const float* __restrict__ A2, const bf16* __restrict__ WT2,
    const float* __restrict__ bias2, void* __restrict__ C2,
    int nblk1)
{
    const float* A; const bf16* WT; const float* bias; void* Cv;
    int N, ntn, bidx, mode;
    if ((int)blockIdx.x < nblk1) {
        A = A1; WT = WT1; bias = bias1; Cv = C1; N = 256; ntn = 2;
        bidx = blockIdx.x; mode = 1;
    } else {
        A = A2; WT = WT2; bias = bias2; Cv = C2; N = 384; ntn = 3;
        bidx = blockIdx.x - nblk1; mode = 0;
    }
    const int nmt = (BS * NQ) / 128;      // 340 (same M for both problems)
    const int bmt = bidx % nmt;           // row-fastest
    const int bnt = bidx / nmt;
    const int bm = bmt * 128, bn = bnt * 128;
    const int K = 256;

    __shared__ __align__(16) bf16 Bs[2][128 * 32];           // 2x8 KB
    __shared__ __align__(16) float Asf[2][128 * 32];         // 2x16 KB, chunk-swizzled

    const int tid = threadIdx.x;
    const int lane = tid & 63, wv = tid >> 6;
    const int wr = wv >> 1, wc = wv & 1;
    const int quad = lane >> 4, l16 = lane & 15;

    f32x4 acc[4][4];
    #pragma unroll
    for (int i = 0; i < 4; i++)
        #pragma unroll
        for (int j = 0; j < 4; j++)
            acc[i][j] = (f32x4){0.f, 0.f, 0.f, 0.f};

    const int b_row = tid >> 2, b_chunk = tid & 3;
    const int a_row8 = tid >> 3, a_phys = tid & 7;
    constexpr int NB = 6;   // 4 A + 2 B global_load_lds per thread per step

    auto stage = [&](int buf, int k0) {
        #pragma unroll
        for (int p = 0; p < 4; p++) {
            int row = a_row8 + p * 32;
            int csrc = a_phys ^ (row & 7);       // inverse-swizzled source chunk
            GLOAD_LDS16(&A[(size_t)(bm + row) * K + k0 + csrc * 4],
                        (unsigned char*)&Asf[buf][0] + p * 4096 + tid * 16);
        }
        #pragma unroll
        for (int p = 0; p < 2; p++) {
            int row = b_row + p * 64;
            GLOAD_LDS16(&WT[(size_t)(bn + row) * K + k0 + b_chunk * 8],
                        (unsigned char*)&Bs[buf][0] + p * 4096 + tid * 16);
        }
    };

    stage(0, 0);
    int cur = 0;
    for (int t = 0; t < 8; t++) {
        __builtin_amdgcn_s_barrier();
        if (t + 1 < 8) {
            stage(cur ^ 1, (t + 1) << 5);
            asm volatile("s_waitcnt vmcnt(%0)" :: "n"(NB) : "memory");
        } else {
            asm volatile("s_waitcnt vmcnt(0)" ::: "memory");
        }
        __builtin_amdgcn_s_barrier();

        bf16x8 af[4], bfr[4];
        #pragma unroll
        for (int mi = 0; mi < 4; mi++) {
            int r = wr * 64 + mi * 16 + l16;
            int g = r & 7;
            f32x4 u0 = *(const f32x4*)&Asf[cur][r * 32 + ((2 * quad) ^ g) * 4];
            f32x4 u1 = *(const f32x4*)&Asf[cur][r * 32 + ((2 * quad + 1) ^ g) * 4];
            bf16x8 hh;
            hh[0] = (bf16)u0[0]; hh[1] = (bf16)u0[1]; hh[2] = (bf16)u0[2]; hh[3] = (bf16)u0[3];
            hh[4] = (bf16)u1[0]; hh[5] = (bf16)u1[1]; hh[6] = (bf16)u1[2]; hh[7] = (bf16)u1[3];
            af[mi] = hh;
        }
        #pragma unroll
        for (int ni = 0; ni < 4; ni++) {
            int r = wc * 64 + ni * 16 + l16;
            bfr[ni] = *(const bf16x8*)&Bs[cur][r * 32 + quad * 8];
        }
        #pragma unroll
        for (int mi = 0; mi < 4; mi++)
            #pragma unroll
            for (int ni = 0; ni < 4; ni++)
                acc[mi][ni] = __builtin_amdgcn_mfma_f32_16x16x32_bf16(
                    af[mi], bfr[ni], acc[mi][ni], 0, 0, 0);
        cur ^= 1;
    }

    // epilogue
    #pragma unroll
    for (int mi = 0; mi < 4; mi++) {
        #pragma unroll
        for (int ni = 0; ni < 4; ni++) {
            const int col = bn + wc * 64 + ni * 16 + l16;
            const int row0 = bm + wr * 64 + mi * 16 + quad * 4;
            const float bc = bias[col];
            #pragma unroll
            for (int r = 0; r < 4; r++) {
                float v = acc[mi][ni][r] + bc;
                if (mode == 0) {
                    ((float*)Cv)[(size_t)(row0 + r) * N + col] = v;
                } else {
                    int rv = row0 + r;
                    int bb2 = (rv >= V_LEN) ? 1 : 0;
                    int vv = rv - bb2 * V_LEN;
                    ((bf16*)Cv)[((size_t)(bb2 * NH + (col >> 5)) * V_LEN + vv) * 32
                                + (col & 31)] = (bf16)v;
                }
            }
        }
    }
}

// 8-channel bf16->f32 unpack + weighted accumulate into 4 packed f32x2
__device__ inline void acc8(const uint4& rr, float ww,
                            f32x2& a01, f32x2& a23, f32x2& a45, f32x2& a67)
{
    f32x2 v;
    v[0] = __uint_as_float(rr.x << 16); v[1] = __uint_as_float(rr.x & 0xFFFF0000u); a01 += v * ww;
    v[0] = __uint_as_float(rr.y << 16); v[1] = __uint_as_float(rr.y & 0xFFFF0000u); a23 += v * ww;
    v[0] = __uint_as_float(rr.z << 16); v[1] = __uint_as_float(rr.z & 0xFFFF0000u); a45 += v * ww;
    v[0] = __uint_as_float(rr.w << 16); v[1] = __uint_as_float(rr.w & 0xFFFF0000u); a67 += v * ww;
}

// ---------------- Fused deform sampling + output projection.
// 16 queries per 1024-thread block (one wave per query). Each wave:
// in-register softmax -> sample precompute -> cacheline-aligned gather
// -> bf16 row into s_samp. Then 16 waves cooperatively compute
// out[16q,256] = s_samp @ WTu^T + b_out (8 MFMA/wave, B from L2-hot global).
__global__ __launch_bounds__(1024, 4) void deform_out(
    const bf16* __restrict__ vproj, const float* __restrict__ offaw,
    const float* __restrict__ refp, const bf16* __restrict__ WTu,
    const float* __restrict__ b_out, float* __restrict__ out)
{
    const int wv = threadIdx.x >> 6;          // wave = query slot (0..15)
    const int t = threadIdx.x & 63;           // lane
    const int b = blockIdx.y;
    const int q0 = blockIdx.x * 16;
    const int bq = b * NQ + q0 + wv;

    __shared__ __align__(16) float s_w[16][128][4];   // 32 KB
    __shared__ __align__(16) int   s_idx[16][128];    // 8 KB
    __shared__ __align__(16) bf16  s_samp[16][264];   // 8.25 KB (+8 pad: conflict-free reads)

    const float* row = offaw + (size_t)bq * 384;

    // ---- in-register softmax: lane owns (h = t&7, e = t>>3); logits for lp=e, e+8
    const int hp = t & 7, e = t >> 3;
    float l0 = row[256 + hp * 16 + e];
    float l1 = row[256 + hp * 16 + e + 8];
    float m = fmaxf(l0, l1);
    m = fmaxf(m, __shfl_xor(m, 8));
    m = fmaxf(m, __shfl_xor(m, 16));
    m = fmaxf(m, __shfl_xor(m, 32));
    float e0 = __expf(l0 - m), e1 = __expf(l1 - m);
    float ssum = e0 + e1;
    ssum += __shfl_xor(ssum, 8);
    ssum += __shfl_xor(ssum, 16);
    ssum += __shfl_xor(ssum, 32);
    float rs = 1.0f / ssum;
    float awv[2] = {e0 * rs, e1 * rs};

    // ---- precompute 128 samples as (pair base, 4 slot weights); d == t + 64*sI
    #pragma unroll
    for (int sI = 0; sI < 2; sI++) {
        int lp = e + sI * 8;
        int l = lp >> 2;
        int Wl = 128 >> l, Hl = 128 >> l;
        int st = (l == 0) ? 0 : (l == 1) ? 16384 : (l == 2) ? 20480 : 21504;
        float2 rp = *(const float2*)&refp[((size_t)bq * 4 + l) * 2];
        float2 oxy = *(const float2*)&row[hp * 32 + lp * 2];
        float fW = (float)Wl, fH = (float)Hl;
        float x = (rp.x + oxy.x / fW) * fW - 0.5f;
        float y = (rp.y + oxy.y / fH) * fH - 0.5f;
        float xf = floorf(x), yf = floorf(y);
        int x0 = (int)xf, y0 = (int)yf;
        float wx1 = x - xf, wx0 = 1.f - wx1;
        float wy1 = y - yf, wy0 = 1.f - wy1;
        float aw = awv[sI];
        float wx0p = ((x0 >= 0) && (x0 < Wl)) ? wx0 : 0.f;
        float wx1p = ((x0 + 1 >= 0) && (x0 + 1 < Wl)) ? wx1 : 0.f;
        float wy0p = ((y0 >= 0) && (y0 < Hl)) ? wy0 : 0.f;
        float wy1p = ((y0 + 1 >= 0) && (y0 + 1 < Hl)) ? wy1 : 0.f;
        int px = min(max(x0, 0), Wl - 2), py = min(max(y0, 0), Hl - 2);
        int cx0 = min(max(x0, 0), Wl - 1), cx1 = min(max(x0 + 1, 0), Wl - 1);
        int cy0 = min(max(y0, 0), Hl - 1), cy1 = min(max(y0 + 1, 0), Hl - 1);
        float sx0 = ((cx0 == px) ? wx0p : 0.f) + ((cx1 == px) ? wx1p : 0.f);
        float sx1 = ((cx0 == px + 1) ? wx0p : 0.f) + ((cx1 == px + 1) ? wx1p : 0.f);
        float sy0 = ((cy0 == py) ? wy0p : 0.f) + ((cy1 == py) ? wy1p : 0.f);
        float sy1 = ((cy0 == py + 1) ? wy0p : 0.f) + ((cy1 == py + 1) ? wy1p : 0.f);
        int d = lp * 8 + hp;  // == t + 64*sI
        s_idx[wv][d] = st + py * Wl + px;
        s_w[wv][d][0] = sy0 * sx0 * aw;
        s_w[wv][d][1] = sy0 * sx1 * aw;
        s_w[wv][d][2] = sy1 * sx0 * aw;
        s_w[wv][d][3] = sy1 * sx1 * aw;
    }
    // same-wave LDS RAW: ordered via lgkmcnt (compiler-inserted), no barrier needed

    // ---- gather: 8 lanes per head (h = t>>3, j = t&7).
    const int h = t >> 3, j = t & 7;
    const bf16* vb = vproj + ((size_t)(b * NH + h) * V_LEN) * 32 + j * 8;

    f32x2 a01 = {0.f, 0.f}, a23 = {0.f, 0.f}, a45 = {0.f, 0.f}, a67 = {0.f, 0.f};
    #pragma unroll
    for (int lp = 0; lp < 16; lp++) {
        const int Wl = 128 >> (lp >> 2);
        const int d = lp * 8 + h;
        const int base = s_idx[wv][d];
        const float4 w4 = *(const float4*)&s_w[wv][d][0];
        const bf16* p0 = vb + (size_t)base * 32;
        uint4 r0 = *(const uint4*)p0;             // row py
        uint4 r1 = *(const uint4*)(p0 + Wl * 32); // row py+1
        const bool xs = (j & 4) != 0;
        float wA = xs ? w4.y : w4.x;
        float wB = xs ? w4.w : w4.z;
        acc8(r0, wA, a01, a23, a45, a67);
        acc8(r1, wB, a01, a23, a45, a67);
    }

    // combine x-slots (lanes j and j^4 hold same channels) -> bf16 row in LDS
    float s[8] = {a01[0], a01[1], a23[0], a23[1], a45[0], a45[1], a67[0], a67[1]};
    #pragma unroll
    for (int i = 0; i < 8; i++) s[i] += __shfl_xor(s[i], 4);

    if ((t & 4) == 0) {
        bf16x8 o;
        #pragma unroll
        for (int i = 0; i < 8; i++) o[i] = (bf16)s[i];
        *(bf16x8*)&s_samp[wv][h * 32 + (t & 3) * 8] = o;
    }
    __syncthreads();

    // ---- output projection: wave wv owns cols wv*16..wv*16+15
    const int quad = t >> 4, l16 = t & 15;
    const int col = wv * 16 + l16;
    const bf16* wrow = WTu + (size_t)col * 256;
    f32x4 oacc = (f32x4){0.f, 0.f, 0.f, 0.f};
    #pragma unroll
    for (int ks = 0; ks < 8; ks++) {
        bf16x8 afr = *(const bf16x8*)&s_samp[l16][ks * 32 + quad * 8];
        bf16x8 bfr = *(const bf16x8*)&wrow[ks * 32 + quad * 8];
        oacc = __builtin_amdgcn_mfma_f32_16x16x32_bf16(afr, bfr, oacc, 0, 0, 0);
    }
    const float bc = b_out[col];
    #pragma unroll
    for (int r = 0; r < 4; r++)
        out[(size_t)(b * NQ + q0 + quad * 4 + r) * 256 + col] = oacc[r] + bc;
}

extern "C" void kernel_launch(void* const* d_in, const int* in_sizes, int n_in,
                              void* d_out, int out_size, void* d_ws, size_t ws_size,
                              hipStream_t stream)
{
    const float* query  = (const float*)d_in[0];
    const float* refp   = (const float*)d_in[1];
    const float* value  = (const float*)d_in[2];
    const float* W_off  = (const float*)d_in[3];
    const float* b_off  = (const float*)d_in[4];
    const float* W_attn = (const float*)d_in[5];
    const float* b_attn = (const float*)d_in[6];
    const float* W_v    = (const float*)d_in[7];
    const float* b_v    = (const float*)d_in[8];
    const float* W_out  = (const float*)d_in[9];
    const float* b_out  = (const float*)d_in[10];
    float* out = (float*)d_out;

    const int M = BS * NQ;  // 43520

    char* ws = (char*)d_ws;
    bf16*  WTv   = (bf16*)ws;                      ws += 256 * 256 * 2;
    bf16*  WToa  = (bf16*)ws;                      ws += 384 * 256 * 2;
    bf16*  WTu   = (bf16*)ws;                      ws += 256 * 256 * 2;
    float* bcat  = (float*)ws;                     ws += 384 * 4;
    bf16*  vproj = (bf16*)ws;                      ws += (size_t)M * 256 * 2;   // per-head layout
    float* offaw = (float*)ws;                     ws += (size_t)M * 384 * 4;

    cast_all<<<57, 256, 0, stream>>>(W_v, W_off, W_attn, W_out, b_off, b_attn,
                                     WTv, WToa, WTu, bcat);

    // merged: vproj (680 blocks) + offaw (1020 blocks)
    const int nblk1 = (M / 128) * 2;
    gemm_dual<<<nblk1 + (M / 128) * 3, 256, 0, stream>>>(
        value, WTv, b_v, vproj,
        query, WToa, bcat, offaw, nblk1);

    // fused sampling + output projection
    deform_out<<<dim3(NQ / 16, BS), dim3(1024), 0, stream>>>(
        vproj, offaw, refp, WTu, b_out, out);
}

// Round 7
// 268.558 us; speedup vs baseline: 1.1231x; 1.1231x over previous
//
#include <hip/hip_runtime.h>
#include <math.h>

#define BS 2
#define NQ 21760
#define V_LEN 21760
#define EMBED 256
#define NH 8
#define NL 4
#define NP 4
#define HD 32

typedef __bf16 bf16;
typedef __bf16 bf16x8 __attribute__((ext_vector_type(8)));
typedef __bf16 bf16x4 __attribute__((ext_vector_type(4)));
typedef float f32x4 __attribute__((ext_vector_type(4)));
typedef float f32x2 __attribute__((ext_vector_type(2)));
typedef unsigned int u32;

// async global->LDS, 16B per lane. LDS dest must be lane-linear (base + lane*16).
#define GLOAD_LDS16(gp, lp_) \
    __builtin_amdgcn_global_load_lds( \
        (const __attribute__((address_space(1))) unsigned int*)(gp), \
        (__attribute__((address_space(3))) unsigned int*)(lp_), 16, 0, 0)

// ---------------- fused prologue: LDS-tiled transpose+cast of all weights + bias concat
__global__ __launch_bounds__(256) void cast_all(
    const float* __restrict__ W_v, const float* __restrict__ W_off,
    const float* __restrict__ W_attn, const float* __restrict__ W_out,
    const float* __restrict__ b_off, const float* __restrict__ b_attn,
    bf16* __restrict__ WTv, bf16* __restrict__ WToa, bf16* __restrict__ WTu,
    float* __restrict__ bcat)
{
    const int bid = blockIdx.x;
    const int tid = threadIdx.x;
    if (bid == 56) {
        if (tid < 384) bcat[tid] = (tid < 256) ? b_off[tid] : b_attn[tid - 256];
        return;
    }
    const float* W; bf16* WT; int N, tile;
    if (bid < 16)      { W = W_v;    WT = WTv;           N = 256; tile = bid; }
    else if (bid < 32) { W = W_off;  WT = WToa;          N = 256; tile = bid - 16; }
    else if (bid < 40) { W = W_attn; WT = WToa + 65536;  N = 128; tile = bid - 32; }
    else               { W = W_out;  WT = WTu;           N = 256; tile = bid - 40; }
    const int ntn = N >> 6;
    const int k0 = (tile / ntn) * 64, n0 = (tile % ntn) * 64;

    __shared__ float lds[64][65];
    const int c = tid & 63, r4 = tid >> 6;
    #pragma unroll
    for (int p = 0; p < 16; p++) {
        int rr = r4 + p * 4;
        lds[rr][c] = W[(size_t)(k0 + rr) * N + n0 + c];   // coalesced 256B rows
    }
    __syncthreads();
    #pragma unroll
    for (int p = 0; p < 16; p++) {
        int i = r4 + p * 4;                                // n index
        WT[(size_t)(n0 + i) * 256 + k0 + c] = (bf16)lds[c][i];  // coalesced 128B rows
    }
}

// ---------------- bf16 MFMA GEMM: C[M,N] = A[M,K] @ WT^T + bias
// OUT_MODE: 0 = fp32 linear, 1 = bf16 linear, 2 = bf16 per-head vproj layout
//           vproj[b][h][v][32] with global row rv -> (b = rv>=V_LEN, v = rv - b*V_LEN)
template<bool A_F32, int OUT_MODE>
__global__ __launch_bounds__(256) void gemm_mfma(
    const void* __restrict__ Av, const bf16* __restrict__ WT,
    const float* __restrict__ bias, void* __restrict__ Cv,
    int N, int K, int ntn)
{
    const int nmt = gridDim.x / ntn;
    const int bmt = blockIdx.x % nmt;     // row-fastest
    const int bnt = blockIdx.x / nmt;
    const int bm = bmt * 128, bn = bnt * 128;

    __shared__ __align__(16) bf16 Bs[2][128 * 32];                       // 2x8 KB
    __shared__ __align__(16) unsigned char AsRaw[2][A_F32 ? 128 * 32 * 4
                                                         : 128 * 32 * 2];

    const int tid = threadIdx.x;
    const int lane = tid & 63, wv = tid >> 6;
    const int wr = wv >> 1, wc = wv & 1;
    const int quad = lane >> 4, l16 = lane & 15;

    f32x4 acc[4][4];
    #pragma unroll
    for (int i = 0; i < 4; i++)
        #pragma unroll
        for (int j = 0; j < 4; j++)
            acc[i][j] = (f32x4){0.f, 0.f, 0.f, 0.f};

    const int b_row = tid >> 2, b_chunk = tid & 3;   // bf16 staging: byte = p*4096 + tid*16
    const int a_row8 = tid >> 3, a_phys = tid & 7;   // f32 staging:  byte = p*4096 + tid*16
    constexpr int NB = A_F32 ? 6 : 4;                // global_load_lds per thread per step

    auto stage = [&](int buf, int k0) {
        if constexpr (A_F32) {
            const float* A = (const float*)Av;
            #pragma unroll
            for (int p = 0; p < 4; p++) {
                int row = a_row8 + p * 32;
                int csrc = a_phys ^ (row & 7);       // inverse-swizzled source chunk
                GLOAD_LDS16(&A[(size_t)(bm + row) * K + k0 + csrc * 4],
                            &AsRaw[buf][p * 4096 + tid * 16]);
            }
        } else {
            const bf16* A = (const bf16*)Av;
            #pragma unroll
            for (int p = 0; p < 2; p++) {
                int row = b_row + p * 64;
                GLOAD_LDS16(&A[(size_t)(bm + row) * K + k0 + b_chunk * 8],
                            &AsRaw[buf][p * 4096 + tid * 16]);
            }
        }
        #pragma unroll
        for (int p = 0; p < 2; p++) {
            int row = b_row + p * 64;
            GLOAD_LDS16(&WT[(size_t)(bn + row) * K + k0 + b_chunk * 8],
                        (unsigned char*)&Bs[buf][0] + p * 4096 + tid * 16);
        }
    };

    const int nt = K >> 5;   // 8
    stage(0, 0);
    int cur = 0;
    for (int t = 0; t < nt; t++) {
        __builtin_amdgcn_s_barrier();               // prev step's LDS reads all done
        if (t + 1 < nt) {
            stage(cur ^ 1, (t + 1) << 5);           // prefetch next tile (stays in flight)
            asm volatile("s_waitcnt vmcnt(%0)" :: "n"(NB) : "memory");  // cur tile landed
        } else {
            asm volatile("s_waitcnt vmcnt(0)" ::: "memory");
        }
        __builtin_amdgcn_s_barrier();               // all waves' cur-tile loads landed

        bf16x8 af[4], bfr[4];
        if constexpr (A_F32) {
            const float* Asf = (const float*)&AsRaw[cur][0];  // [128][32] f32, chunk-swizzled
            #pragma unroll
            for (int mi = 0; mi < 4; mi++) {
                int r = wr * 64 + mi * 16 + l16;
                int g = r & 7;
                f32x4 u0 = *(const f32x4*)&Asf[r * 32 + ((2 * quad) ^ g) * 4];
                f32x4 u1 = *(const f32x4*)&Asf[r * 32 + ((2 * quad + 1) ^ g) * 4];
                bf16x8 hh;
                hh[0] = (bf16)u0[0]; hh[1] = (bf16)u0[1]; hh[2] = (bf16)u0[2]; hh[3] = (bf16)u0[3];
                hh[4] = (bf16)u1[0]; hh[5] = (bf16)u1[1]; hh[6] = (bf16)u1[2]; hh[7] = (bf16)u1[3];
                af[mi] = hh;
            }
        } else {
            const bf16* Asb = (const bf16*)&AsRaw[cur][0];    // [128][32] bf16, linear
            #pragma unroll
            for (int mi = 0; mi < 4; mi++) {
                int r = wr * 64 + mi * 16 + l16;
                af[mi] = *(const bf16x8*)&Asb[r * 32 + quad * 8];
            }
        }
        #pragma unroll
        for (int ni = 0; ni < 4; ni++) {
            int r = wc * 64 + ni * 16 + l16;
            bfr[ni] = *(const bf16x8*)&Bs[cur][r * 32 + quad * 8];
        }
        #pragma unroll
        for (int mi = 0; mi < 4; mi++)
            #pragma unroll
            for (int ni = 0; ni < 4; ni++)
                acc[mi][ni] = __builtin_amdgcn_mfma_f32_16x16x32_bf16(
                    af[mi], bfr[ni], acc[mi][ni], 0, 0, 0);
        cur ^= 1;
    }

    // epilogue
    #pragma unroll
    for (int mi = 0; mi < 4; mi++) {
        #pragma unroll
        for (int ni = 0; ni < 4; ni++) {
            const int col = bn + wc * 64 + ni * 16 + l16;
            const int row0 = bm + wr * 64 + mi * 16 + quad * 4;
            const float bc = bias[col];
            #pragma unroll
            for (int r = 0; r < 4; r++) {
                float v = acc[mi][ni][r] + bc;
                if constexpr (OUT_MODE == 0) {
                    ((float*)Cv)[(size_t)(row0 + r) * N + col] = v;
                } else if constexpr (OUT_MODE == 1) {
                    ((bf16*)Cv)[(size_t)(row0 + r) * N + col] = (bf16)v;
                } else {
                    int rv = row0 + r;
                    int bb = (rv >= V_LEN) ? 1 : 0;
                    int vv = rv - bb * V_LEN;
                    ((bf16*)Cv)[((size_t)(bb * NH + (col >> 5)) * V_LEN + vv) * 32
                                + (col & 31)] = (bf16)v;
                }
            }
        }
    }
}

// 8-channel bf16->f32 unpack + weighted accumulate into 4 packed f32x2
__device__ inline void acc8(const uint4& rr, float ww,
                            f32x2& a01, f32x2& a23, f32x2& a45, f32x2& a67)
{
    f32x2 v;
    v[0] = __uint_as_float(rr.x << 16); v[1] = __uint_as_float(rr.x & 0xFFFF0000u); a01 += v * ww;
    v[0] = __uint_as_float(rr.y << 16); v[1] = __uint_as_float(rr.y & 0xFFFF0000u); a23 += v * ww;
    v[0] = __uint_as_float(rr.z << 16); v[1] = __uint_as_float(rr.z & 0xFFFF0000u); a45 += v * ww;
    v[0] = __uint_as_float(rr.w << 16); v[1] = __uint_as_float(rr.w & 0xFFFF0000u); a67 += v * ww;
}

// ---------------- Deformable sampling split per (batch, head) for XCD-L2 residency.
// Block = 256 thr = 4 waves; block handles 16 queries x ONE (b,h).
// vproj slab per (b,h) = V_LEN*64B = 2.72 MB < 4 MB per-XCD L2.
// blockIdx: low 3 bits -> (h-low, b) -> XCD via %8 round-robin; h-msb in TOP
// grid bits so each XCD streams one resident slab for half the grid.
// Per wave: 4 queries. Lane (qq=t>>4, s=t&15): softmax over s (16-lane groups),
// one sample precompute per lane. Gather: sample's 2x128B rows spread over its
// query's 16 lanes (chgrp=t&3, xslot=bit2, rowsel=bit3); shfl combine.
__global__ __launch_bounds__(256) void deform_head(
    const bf16* __restrict__ vproj, const float* __restrict__ offaw,
    const float* __restrict__ refp, bf16* __restrict__ sampled)
{
    const int gid = blockIdx.x;
    const int idx8 = gid & 7;                 // -> XCD (round-robin heuristic)
    const int mid = gid >> 3;                 // 0 .. 2*NQ/16-1
    const int qg = mid % (NQ / 16);
    const int hsel = mid / (NQ / 16);         // 0 or 1 (grid-half)
    const int h = (idx8 >> 1) + (hsel << 2);
    const int b = idx8 & 1;

    const int wv = threadIdx.x >> 6;
    const int t = threadIdx.x & 63;
    const int qq = t >> 4, s = t & 15;
    const int q = qg * 16 + wv * 4 + qq;
    const int bq = b * NQ + q;
    const int wq = wv * 4 + qq;

    __shared__ __align__(16) float s_w[16][16][4];   // 4 KB
    __shared__ int s_idx[16][16];                    // 1 KB

    const float* row = offaw + (size_t)bq * 384;

    // ---- per-head softmax over 16 logits (within 16-lane groups)
    float lg = row[256 + h * 16 + s];
    float m = lg;
    m = fmaxf(m, __shfl_xor(m, 1));
    m = fmaxf(m, __shfl_xor(m, 2));
    m = fmaxf(m, __shfl_xor(m, 4));
    m = fmaxf(m, __shfl_xor(m, 8));
    float ev = __expf(lg - m);
    float ssum = ev;
    ssum += __shfl_xor(ssum, 1);
    ssum += __shfl_xor(ssum, 2);
    ssum += __shfl_xor(ssum, 4);
    ssum += __shfl_xor(ssum, 8);
    float aw = ev * (1.0f / ssum);

    // ---- one sample per lane: pair base + 4 slot weights (border-exact)
    {
        int l = s >> 2;
        int Wl = 128 >> l, Hl = Wl;
        int st = (l == 0) ? 0 : (l == 1) ? 16384 : (l == 2) ? 20480 : 21504;
        float2 rp = *(const float2*)&refp[((size_t)bq * 4 + l) * 2];
        float2 oxy = *(const float2*)&row[h * 32 + s * 2];
        float fW = (float)Wl, fH = (float)Hl;
        float x = (rp.x + oxy.x / fW) * fW - 0.5f;
        float y = (rp.y + oxy.y / fH) * fH - 0.5f;
        float xf = floorf(x), yf = floorf(y);
        int x0 = (int)xf, y0 = (int)yf;
        float wx1 = x - xf, wx0 = 1.f - wx1;
        float wy1 = y - yf, wy0 = 1.f - wy1;
        float wx0p = ((x0 >= 0) && (x0 < Wl)) ? wx0 : 0.f;
        float wx1p = ((x0 + 1 >= 0) && (x0 + 1 < Wl)) ? wx1 : 0.f;
        float wy0p = ((y0 >= 0) && (y0 < Hl)) ? wy0 : 0.f;
        float wy1p = ((y0 + 1 >= 0) && (y0 + 1 < Hl)) ? wy1 : 0.f;
        int px = min(max(x0, 0), Wl - 2), py = min(max(y0, 0), Hl - 2);
        int cx0 = min(max(x0, 0), Wl - 1), cx1 = min(max(x0 + 1, 0), Wl - 1);
        int cy0 = min(max(y0, 0), Hl - 1), cy1 = min(max(y0 + 1, 0), Hl - 1);
        float sx0 = ((cx0 == px) ? wx0p : 0.f) + ((cx1 == px) ? wx1p : 0.f);
        float sx1 = ((cx0 == px + 1) ? wx0p : 0.f) + ((cx1 == px + 1) ? wx1p : 0.f);
        float sy0 = ((cy0 == py) ? wy0p : 0.f) + ((cy1 == py) ? wy1p : 0.f);
        float sy1 = ((cy0 == py + 1) ? wy0p : 0.f) + ((cy1 == py + 1) ? wy1p : 0.f);
        s_idx[wq][s] = st + py * Wl + px;
        s_w[wq][s][0] = sy0 * sx0 * aw;
        s_w[wq][s][1] = sy0 * sx1 * aw;
        s_w[wq][s][2] = sy1 * sx0 * aw;
        s_w[wq][s][3] = sy1 * sx1 * aw;
    }
    // wave-local LDS RAW (each wave reads only its own region) -> no block barrier

    // ---- gather: 16 lanes per query; lane covers (rowsel, xslot, chgrp)
    const int chgrp = t & 3;
    const int xslot = (t >> 2) & 1;
    const int rowsel = (t >> 3) & 1;
    const int widx = rowsel * 2 + xslot;
    const bf16* vb = vproj + (size_t)(b * NH + h) * V_LEN * 32;

    f32x2 a01 = {0.f, 0.f}, a23 = {0.f, 0.f}, a45 = {0.f, 0.f}, a67 = {0.f, 0.f};
    #pragma unroll
    for (int i = 0; i < 16; i++) {
        const int Wl = 128 >> (i >> 2);       // compile-time per unrolled iter
        int base = s_idx[wq][i];              // broadcast within 16-lane group
        float w = s_w[wq][i][widx];
        const bf16* p = vb + (size_t)(base + rowsel * Wl + xslot) * 32 + chgrp * 8;
        uint4 r = *(const uint4*)p;
        acc8(r, w, a01, a23, a45, a67);
    }

    // combine xslot (bit2) and rowsel (bit3)
    float sarr[8] = {a01[0], a01[1], a23[0], a23[1], a45[0], a45[1], a67[0], a67[1]};
    #pragma unroll
    for (int i = 0; i < 8; i++) {
        sarr[i] += __shfl_xor(sarr[i], 4);
        sarr[i] += __shfl_xor(sarr[i], 8);
    }

    if ((t & 12) == 0) {                      // one lane per (query, chgrp)
        bf16x8 o;
        #pragma unroll
        for (int i = 0; i < 8; i++) o[i] = (bf16)sarr[i];
        *(bf16x8*)&sampled[(size_t)bq * 256 + h * 32 + chgrp * 8] = o;
    }
}

extern "C" void kernel_launch(void* const* d_in, const int* in_sizes, int n_in,
                              void* d_out, int out_size, void* d_ws, size_t ws_size,
                              hipStream_t stream)
{
    const float* query  = (const float*)d_in[0];
    const float* refp   = (const float*)d_in[1];
    const float* value  = (const float*)d_in[2];
    const float* W_off  = (const float*)d_in[3];
    const float* b_off  = (const float*)d_in[4];
    const float* W_attn = (const float*)d_in[5];
    const float* b_attn = (const float*)d_in[6];
    const float* W_v    = (const float*)d_in[7];
    const float* b_v    = (const float*)d_in[8];
    const float* W_out  = (const float*)d_in[9];
    const float* b_out  = (const float*)d_in[10];
    float* out = (float*)d_out;

    const int M = BS * NQ;  // 43520

    char* ws = (char*)d_ws;
    bf16*  WTv   = (bf16*)ws;                      ws += 256 * 256 * 2;
    bf16*  WToa  = (bf16*)ws;                      ws += 384 * 256 * 2;
    bf16*  WTu   = (bf16*)ws;                      ws += 256 * 256 * 2;
    float* bcat  = (float*)ws;                     ws += 384 * 4;
    bf16*  vproj = (bf16*)ws;                      ws += (size_t)M * 256 * 2;   // per-head layout
    float* offaw = (float*)ws;                     ws += (size_t)M * 384 * 4;
    bf16*  samp  = (bf16*)ws;                      ws += (size_t)M * 256 * 2;

    cast_all<<<57, 256, 0, stream>>>(W_v, W_off, W_attn, W_out, b_off, b_attn,
                                     WTv, WToa, WTu, bcat);

    // vproj = bf16(value @ W_v + b_v), per-head layout [b][h][v][32]
    gemm_mfma<true, 2><<<(M / 128) * 2, 256, 0, stream>>>(value, WTv, b_v, vproj, 256, 256, 2);
    // offaw = query @ [W_off | W_attn] + [b_off | b_attn]   (fp32 out)
    gemm_mfma<true, 0><<<(M / 128) * 3, 256, 0, stream>>>(query, WToa, bcat, offaw, 384, 256, 3);
    // softmax + deformable sampling -> bf16, per-(b,h) XCD-resident blocks
    deform_head<<<2 * NH * (NQ / 16), 256, 0, stream>>>(vproj, offaw, refp, samp);
    // out = sampled @ W_out + b_out  (fp32 out)
    gemm_mfma<false, 0><<<(M / 128) * 2, 256, 0, stream>>>(samp, WTu, b_out, out, 256, 256, 2);
}